// Round 4
// baseline (288.743 us; speedup 1.0000x reference)
//
#include <hip/hip_runtime.h>

typedef _Float16 h16x8 __attribute__((ext_vector_type(8)));
typedef _Float16 h16x4 __attribute__((ext_vector_type(4)));
typedef _Float16 h16x2 __attribute__((ext_vector_type(2)));
typedef float    fx4   __attribute__((ext_vector_type(4)));

static __device__ __forceinline__ fx4 mfma16(h16x8 a, h16x8 b, fx4 c) {
  return __builtin_amdgcn_mfma_f32_16x16x32_f16(a, b, c, 0, 0, 0);
}
static __device__ __forceinline__ h16x2 splat2(float v) {
  const _Float16 h = (_Float16)v; h16x2 r; r[0] = h; r[1] = h; return r;
}
union ABfrag { h16x2 p[4]; h16x8 v; };

// ---------------------------------------------------------------------------
// d_ws layout, per lane (stride 512 halves = 1024 B; 64 lanes = 64 KB):
//   16B vec-slot s holds halves [8s, 8s+8):
//     s  0..7  : B2[ct][ks]  phi W2 B-frags, natural rows  k=32ks+8q+j
//     s  8..15 : B3[ct][ks]  phi W3 B-frags, natural rows
//     s 16..23 : R1[ct][ks]  rho W1 B-frags, permuted rows f=16*(p&3)+(p>>2)
//     s 24..31 : R2[ct][ks]  rho W2 B-frags, permuted rows
//     s 32..35 : R3[ct][ks]  rho W3 B-frags (ct<2), permuted rows
//     s 36..45 : layer1 rows: wx[2], wy[2], wvx[2], wvy[2], bb1[2]
//   float offset 184..201: b2[4], 32*b3[4], rb1[4], rb2[4], rb3[2]
// Transpose permutation: C-layout writer (lane c, col-tile ct) stores feature
// f=16*ct+c at position p=4*c+ct (one ds_write_b64); A-layout consumer's
// weight rows use f = 16*(p&3)+(p>>2) so K-order matches (dot order-invariant).
// ---------------------------------------------------------------------------

__global__ __launch_bounds__(64)
void prep_weights(const float* __restrict__ pW1, const float* __restrict__ pb1,
                  const float* __restrict__ pW2, const float* __restrict__ pb2,
                  const float* __restrict__ pW3, const float* __restrict__ pb3,
                  const float* __restrict__ rW1, const float* __restrict__ rb1,
                  const float* __restrict__ rW2, const float* __restrict__ rb2,
                  const float* __restrict__ rW3, const float* __restrict__ rb3,
                  _Float16* __restrict__ ws)
{
  const int lane = threadIdx.x;
  const int q = lane >> 4, c = lane & 15;
  _Float16* W = ws + (size_t)lane * 512;

#pragma unroll
  for (int ct = 0; ct < 4; ++ct)
#pragma unroll
    for (int ks = 0; ks < 2; ++ks)
#pragma unroll
      for (int j = 0; j < 8; ++j) {
        const int p = 32*ks + 8*q + j;
        const int f = 16*(p & 3) + (p >> 2);
        W[      (ct*2 + ks)*8 + j] = (_Float16)pW2[p*64 + 16*ct + c];
        W[ 64 + (ct*2 + ks)*8 + j] = (_Float16)pW3[p*64 + 16*ct + c];
        W[128 + (ct*2 + ks)*8 + j] = (_Float16)rW1[f*64 + 16*ct + c];
        W[192 + (ct*2 + ks)*8 + j] = (_Float16)rW2[f*64 + 16*ct + c];
        if (ct < 2)
          W[256 + (ct*2 + ks)*8 + j] = (_Float16)rW3[f*32 + 16*ct + c];
      }
#pragma unroll
  for (int ks = 0; ks < 2; ++ks)
#pragma unroll
    for (int i = 0; i < 8; ++i) {
      const int f = 32*ks + 8*q + i;
      W[288 + ks*8 + i] = (_Float16)pW1[      f];
      W[304 + ks*8 + i] = (_Float16)pW1[ 64 + f];
      W[320 + ks*8 + i] = (_Float16)pW1[128 + f];
      W[336 + ks*8 + i] = (_Float16)pW1[192 + f];
      W[352 + ks*8 + i] = (_Float16)pb1[      f];
    }
  float* F = (float*)(ws + (size_t)lane * 512) + 184;
#pragma unroll
  for (int ct = 0; ct < 4; ++ct) {
    F[     ct] = pb2[16*ct + c];
    F[ 4 + ct] = 32.f * pb3[16*ct + c];
    F[ 8 + ct] = rb1[16*ct + c];
    F[12 + ct] = rb2[16*ct + c];
  }
#pragma unroll
  for (int ct = 0; ct < 2; ++ct) F[16 + ct] = rb3[16*ct + c];
}

__global__ __launch_bounds__(64, 5)
void deepset_main(const float* __restrict__ x, const float* __restrict__ vel,
                  const _Float16* __restrict__ ws, float* __restrict__ out)
{
  // single wave per block; everything wave-private, no __syncthreads
  __shared__ __align__(16) _Float16 h2T[16][72];   // stride 72 breaks pow2 banks
  __shared__ __align__(16) _Float16 Xlds[16][72];

  const int lane = threadIdx.x & 63;
  const int q    = lane >> 4;
  const int c    = lane & 15;

  const h16x8* V = (const h16x8*)(ws + (size_t)lane * 512);
  const float* F = (const float*)(ws + (size_t)lane * 512) + 184;

  // ---- phi-stage fragments
  h16x8 B2[4][2];
#pragma unroll
  for (int ct = 0; ct < 4; ++ct)
#pragma unroll
    for (int ks = 0; ks < 2; ++ks) B2[ct][ks] = V[ct*2 + ks];
  ABfrag wx[2], wy[2], wvx[2], wvy[2], bbp[2];
#pragma unroll
  for (int ks = 0; ks < 2; ++ks) {
    wx [ks].v = V[36 + ks];
    wy [ks].v = V[38 + ks];
    wvx[ks].v = V[40 + ks];
    wvy[ks].v = V[42 + ks];
    bbp[ks].v = V[44 + ks];
  }
  float b2v[4];
#pragma unroll
  for (int ct = 0; ct < 4; ++ct) b2v[ct] = F[ct];

  const int sBase = blockIdx.x * 8;
  const h16x2 z2 = splat2(0.f);

  // ================= phi + pool: 8 states, barrier-free =================
  float4 xo_cur = ((const float4*)x)[(size_t)sBase*16 + c];   // obstacles 2c,2c+1
  float2 v_cur  = *(const float2*)(vel + 2*(size_t)sBase);    // wave-uniform

#pragma unroll 1
  for (int si = 0; si < 8; ++si) {
    float4 xo_nxt; float2 v_nxt;
    if (si < 7) {
      xo_nxt = ((const float4*)x)[(size_t)(sBase + si + 1)*16 + c];
      v_nxt  = *(const float2*)(vel + 2*(size_t)(sBase + si + 1));
    }
    const h16x2 vxp = splat2(v_cur.x);
    const h16x2 vyp = splat2(v_cur.y);
    h16x2 vbp[2][4];
#pragma unroll
    for (int ks = 0; ks < 2; ++ks)
#pragma unroll
      for (int t = 0; t < 4; ++t)
        vbp[ks][t] = vxp * wvx[ks].p[t] + vyp * wvy[ks].p[t] + bbp[ks].p[t];

    float Xacc[4] = {0.f, 0.f, 0.f, 0.f};
#pragma unroll
    for (int hh = 0; hh < 2; ++hh) {          // obstacle o = 2c + hh
      const h16x2 oxp = splat2(hh ? xo_cur.z : xo_cur.x);
      const h16x2 oyp = splat2(hh ? xo_cur.w : xo_cur.y);
      h16x8 A1[2];
#pragma unroll
      for (int ks = 0; ks < 2; ++ks) {
        ABfrag a;
#pragma unroll
        for (int t = 0; t < 4; ++t) {
          const h16x2 h = oxp * wx[ks].p[t] + oyp * wy[ks].p[t] + vbp[ks][t];
          a.p[t] = __builtin_elementwise_max(h, z2);
        }
        A1[ks] = a.v;
      }
#pragma unroll
      for (int ct = 0; ct < 4; ++ct) {
        fx4 acc = {0.f, 0.f, 0.f, 0.f};
        acc = mfma16(A1[0], B2[ct][0], acc);
        acc = mfma16(A1[1], B2[ct][1], acc);
#pragma unroll
        for (int r = 0; r < 4; ++r)
          Xacc[ct] += fmaxf(acc[r] + b2v[ct], 0.f);
      }
    }
#pragma unroll
    for (int ct = 0; ct < 4; ++ct) {
      float v = Xacc[ct];
      v += __shfl_down(v, 16);
      v += __shfl_down(v, 32);
      if (lane < 16) Xlds[si][16*ct + c] = (_Float16)v;
    }
    xo_cur = xo_nxt;
    v_cur  = v_nxt;
  }

  __builtin_amdgcn_s_waitcnt(0xC07F);          // lgkmcnt(0)
  __builtin_amdgcn_wave_barrier();

  // ---- remaining fragments (loaded late to keep phi-loop pressure low)
  h16x8 B3[4][2], R1[4][2], R2[4][2], R3[2][2];
#pragma unroll
  for (int ct = 0; ct < 4; ++ct)
#pragma unroll
    for (int ks = 0; ks < 2; ++ks) {
      B3[ct][ks] = V[ 8 + ct*2 + ks];
      R1[ct][ks] = V[16 + ct*2 + ks];
      R2[ct][ks] = V[24 + ct*2 + ks];
    }
#pragma unroll
  for (int ct = 0; ct < 2; ++ct)
#pragma unroll
    for (int ks = 0; ks < 2; ++ks) R3[ct][ks] = V[32 + ct*2 + ks];
  float b3s[4], rb1v[4], rb2v[4], rb3v[2];
#pragma unroll
  for (int ct = 0; ct < 4; ++ct) {
    b3s[ct]  = F[ 4 + ct];
    rb1v[ct] = F[ 8 + ct];
    rb2v[ct] = F[12 + ct];
  }
#pragma unroll
  for (int ct = 0; ct < 2; ++ct) rb3v[ct] = F[16 + ct];

  // ---- phi layer 3 over the wave's states (rows 0..7 valid; rows 8..15 are
  // garbage but C[m] depends only on A[m], so they never contaminate)
  h16x8 AX[2];
#pragma unroll
  for (int ks = 0; ks < 2; ++ks)
    AX[ks] = *(const h16x8*)&Xlds[c][32*ks + 8*q];

  fx4 C3[4];
#pragma unroll
  for (int ct = 0; ct < 4; ++ct) {
    fx4 acc = {0.f,0.f,0.f,0.f};
    acc = mfma16(AX[0], B3[ct][0], acc);
    acc = mfma16(AX[1], B3[ct][1], acc);
    C3[ct] = acc;
  }
#pragma unroll
  for (int r = 0; r < 4; ++r) {
    h16x4 pk;
#pragma unroll
    for (int ct = 0; ct < 4; ++ct)
      pk[ct] = (_Float16)(C3[ct][r] + b3s[ct]);   // X = W3^T(sum relu) + 32*b3
    *(h16x4*)&h2T[4*q + r][4*c] = pk;
  }
  __builtin_amdgcn_s_waitcnt(0xC07F);
  __builtin_amdgcn_wave_barrier();
  h16x8 A1r[2];
#pragma unroll
  for (int ks = 0; ks < 2; ++ks)
    A1r[ks] = *(const h16x8*)&h2T[c][32*ks + 8*q];
  __builtin_amdgcn_wave_barrier();

  // ---- rho layer 1
  fx4 D1[4];
#pragma unroll
  for (int ct = 0; ct < 4; ++ct) {
    fx4 acc = {0.f,0.f,0.f,0.f};
    acc = mfma16(A1r[0], R1[ct][0], acc);
    acc = mfma16(A1r[1], R1[ct][1], acc);
    D1[ct] = acc;
  }
#pragma unroll
  for (int r = 0; r < 4; ++r) {
    h16x4 pk;
#pragma unroll
    for (int ct = 0; ct < 4; ++ct)
      pk[ct] = (_Float16)fmaxf(D1[ct][r] + rb1v[ct], 0.f);
    *(h16x4*)&h2T[4*q + r][4*c] = pk;
  }
  __builtin_amdgcn_s_waitcnt(0xC07F);
  __builtin_amdgcn_wave_barrier();
  h16x8 A2r[2];
#pragma unroll
  for (int ks = 0; ks < 2; ++ks)
    A2r[ks] = *(const h16x8*)&h2T[c][32*ks + 8*q];
  __builtin_amdgcn_wave_barrier();

  // ---- rho layer 2
  fx4 D2[4];
#pragma unroll
  for (int ct = 0; ct < 4; ++ct) {
    fx4 acc = {0.f,0.f,0.f,0.f};
    acc = mfma16(A2r[0], R2[ct][0], acc);
    acc = mfma16(A2r[1], R2[ct][1], acc);
    D2[ct] = acc;
  }
#pragma unroll
  for (int r = 0; r < 4; ++r) {
    h16x4 pk;
#pragma unroll
    for (int ct = 0; ct < 4; ++ct)
      pk[ct] = (_Float16)fmaxf(D2[ct][r] + rb2v[ct], 0.f);
    *(h16x4*)&h2T[4*q + r][4*c] = pk;
  }
  __builtin_amdgcn_s_waitcnt(0xC07F);
  __builtin_amdgcn_wave_barrier();
  h16x8 A3r[2];
#pragma unroll
  for (int ks = 0; ks < 2; ++ks)
    A3r[ks] = *(const h16x8*)&h2T[c][32*ks + 8*q];
  __builtin_amdgcn_wave_barrier();

  // ---- rho layer 3 + store (rows 0..7 = valid states -> lanes q<2 store)
  fx4 D3[2];
#pragma unroll
  for (int ct = 0; ct < 2; ++ct) {
    fx4 acc = {0.f,0.f,0.f,0.f};
    acc = mfma16(A3r[0], R3[ct][0], acc);
    acc = mfma16(A3r[1], R3[ct][1], acc);
    D3[ct] = acc;
  }
  if (q < 2) {
    const int srow = sBase + 4*q;
#pragma unroll
    for (int ct = 0; ct < 2; ++ct)
#pragma unroll
      for (int r = 0; r < 4; ++r)
        out[(size_t)(srow + r)*32 + 16*ct + c] = D3[ct][r] + rb3v[ct];
  }
}

extern "C" void kernel_launch(void* const* d_in, const int* in_sizes, int n_in,
                              void* d_out, int out_size, void* d_ws, size_t ws_size,
                              hipStream_t stream) {
  const float* x   = (const float*)d_in[0];
  const float* vel = (const float*)d_in[1];
  const float* pW1 = (const float*)d_in[2];
  const float* pb1 = (const float*)d_in[3];
  const float* pW2 = (const float*)d_in[4];
  const float* pb2 = (const float*)d_in[5];
  const float* pW3 = (const float*)d_in[6];
  const float* pb3 = (const float*)d_in[7];
  const float* rW1 = (const float*)d_in[8];
  const float* rb1 = (const float*)d_in[9];
  const float* rW2 = (const float*)d_in[10];
  const float* rb2 = (const float*)d_in[11];
  const float* rW3 = (const float*)d_in[12];
  const float* rb3 = (const float*)d_in[13];
  float* out = (float*)d_out;
  _Float16* ws = (_Float16*)d_ws;

  prep_weights<<<dim3(1), dim3(64), 0, stream>>>(
      pW1, pb1, pW2, pb2, pW3, pb3, rW1, rb1, rW2, rb2, rW3, rb3, ws);

  const int B = in_sizes[0] / 64;        // x is [B, 64]
  deepset_main<<<dim3(B / 8), dim3(64), 0, stream>>>(x, vel, ws, out);
}

// Round 5
// 134.026 us; speedup vs baseline: 2.1544x; 2.1544x over previous
//
#include <hip/hip_runtime.h>

typedef _Float16 h16x8 __attribute__((ext_vector_type(8)));
typedef _Float16 h16x4 __attribute__((ext_vector_type(4)));
typedef _Float16 h16x2 __attribute__((ext_vector_type(2)));
typedef float    fx4   __attribute__((ext_vector_type(4)));

static __device__ __forceinline__ fx4 mfma16(h16x8 a, h16x8 b, fx4 c) {
  return __builtin_amdgcn_mfma_f32_16x16x32_f16(a, b, c, 0, 0, 0);
}
static __device__ __forceinline__ h16x2 splat2(float v) {
  const _Float16 h = (_Float16)v; h16x2 r; r[0] = h; r[1] = h; return r;
}
union ABfrag { h16x2 p[4]; h16x8 v; };

// State-major phi: MFMA rows = 16 states (lane c <-> state sBase+c), loop over
// the 32 obstacles. Pooling X = sum_o relu(h2[o]+b2) happens IN REGISTERS
// (C-layout: lane c <-> h2-feature 16ct+c, reg r <-> state 4q+r) — no shuffles.
// vel-part of layer 1 computed once per wave. Biases folded into MFMA acc-init.
// All weights read from d_in (cached; d_ws is NOT cached — round-4 lesson).
//
// Transpose permutation (C-layout producer -> A-layout consumer):
// writer (lane c, col-tile ct) stores feature f=16*ct+c at position p=4*c+ct
// (one ds_write_b64); consumer's weight rows are loaded with
// f = 16*(p&3)+(p>>2) so K-order matches (dot products are order-invariant).

__global__ __launch_bounds__(64, 4)
void deepset_main(const float* __restrict__ x,   const float* __restrict__ vel,
                  const float* __restrict__ pW1, const float* __restrict__ pb1,
                  const float* __restrict__ pW2, const float* __restrict__ pb2,
                  const float* __restrict__ pW3, const float* __restrict__ pb3,
                  const float* __restrict__ rW1, const float* __restrict__ rb1,
                  const float* __restrict__ rW2, const float* __restrict__ rb2,
                  const float* __restrict__ rW3, const float* __restrict__ rb3,
                  float* __restrict__ out)
{
  // one wave per block; everything wave-private, no __syncthreads anywhere
  __shared__ __align__(16) float    xT[16][68];   // 16 states x 64 floats (+4 pad)
  __shared__ __align__(16) _Float16 h2T[16][72];  // transpose buffer

  const int lane = threadIdx.x & 63;
  const int q    = lane >> 4;
  const int c    = lane & 15;
  const int sBase = blockIdx.x * 16;

  // ---- stage x tile into LDS (coalesced float4 loads)
  {
    const int s0 = lane >> 2, ch = lane & 3;
#pragma unroll
    for (int k = 0; k < 4; ++k) {
      const float4 g = ((const float4*)x)[(size_t)(sBase + s0)*16 + ch + 4*k];
      *(float4*)&xT[s0][(ch + 4*k)*4] = g;
    }
  }
  const float2 vc = *(const float2*)(vel + 2*(size_t)(sBase + c)); // this lane's state

  // ---- layer-1 constants: lane's features f = 32*ks + 8*q + 2*t (+1)
  // vel-part folded in ONCE per wave (computed in f32, stored packed f16)
  h16x2 wx[2][4], wy[2][4], vbp[2][4];
#pragma unroll
  for (int ks = 0; ks < 2; ++ks)
#pragma unroll
    for (int t = 0; t < 4; ++t) {
      const int f0 = 32*ks + 8*q + 2*t;
#pragma unroll
      for (int e = 0; e < 2; ++e) {
        wx[ks][t][e] = (_Float16)pW1[      f0 + e];
        wy[ks][t][e] = (_Float16)pW1[ 64 + f0 + e];
        vbp[ks][t][e] = (_Float16)fmaf(vc.x, pW1[128 + f0 + e],
                                  fmaf(vc.y, pW1[192 + f0 + e], pb1[f0 + e]));
      }
    }

  // ---- phi W2 B-fragments (natural rows) + b2
  h16x8 B2[4][2];
#pragma unroll
  for (int ct = 0; ct < 4; ++ct)
#pragma unroll
    for (int ks = 0; ks < 2; ++ks) {
      h16x8 f2;
#pragma unroll
      for (int j = 0; j < 8; ++j)
        f2[j] = (_Float16)pW2[(32*ks + 8*q + j)*64 + 16*ct + c];
      B2[ct][ks] = f2;
    }
  float b2v[4];
#pragma unroll
  for (int ct = 0; ct < 4; ++ct) b2v[ct] = pb2[16*ct + c];

  __builtin_amdgcn_s_waitcnt(0xC07F);          // lgkmcnt(0): xT staged
  __builtin_amdgcn_wave_barrier();

  const h16x2 z2 = splat2(0.f);
  float Xacc[4][4] = {};                        // X[state 4q+r][feat 16ct+c]

  // ================= phi + pool: 32 obstacles, LDS-fed, barrier-free ========
  float4 p_cur = *(const float4*)&xT[c][0];     // obstacles 0,1 of state c
#pragma unroll 1
  for (int oo = 0; oo < 16; ++oo) {
    float4 p_nxt;
    if (oo < 15) p_nxt = *(const float4*)&xT[c][4*(oo + 1)];
#pragma unroll
    for (int hh = 0; hh < 2; ++hh) {            // obstacle o = 2*oo + hh
      const h16x2 ox = splat2(hh ? p_cur.z : p_cur.x);
      const h16x2 oy = splat2(hh ? p_cur.w : p_cur.y);
      h16x8 A1[2];                              // h1[state=c][k=32ks+8q+j]
#pragma unroll
      for (int ks = 0; ks < 2; ++ks) {
        ABfrag a;
#pragma unroll
        for (int t = 0; t < 4; ++t) {
          const h16x2 h = ox * wx[ks][t] + oy * wy[ks][t] + vbp[ks][t];
          a.p[t] = __builtin_elementwise_max(h, z2);
        }
        A1[ks] = a.v;
      }
#pragma unroll
      for (int ct = 0; ct < 4; ++ct) {
        fx4 acc = {b2v[ct], b2v[ct], b2v[ct], b2v[ct]};   // bias as acc-init
        acc = mfma16(A1[0], B2[ct][0], acc);
        acc = mfma16(A1[1], B2[ct][1], acc);
#pragma unroll
        for (int r = 0; r < 4; ++r)
          Xacc[ct][r] += fmaxf(acc[r], 0.f);    // pool in registers
      }
    }
    p_cur = p_nxt;
  }

  // ---- tail weights (loaded after the hot loop to cap phi-loop VGPRs)
  h16x8 B3[4][2], R1[4][2], R2[4][2], R3[2][2];
#pragma unroll
  for (int ct = 0; ct < 4; ++ct)
#pragma unroll
    for (int ks = 0; ks < 2; ++ks) {
      h16x8 f3, f1, f2;
#pragma unroll
      for (int j = 0; j < 8; ++j) {
        const int p = 32*ks + 8*q + j;
        const int f = 16*(p & 3) + (p >> 2);     // permuted rows (transposed in)
        f3[j] = (_Float16)pW3[f*64 + 16*ct + c];
        f1[j] = (_Float16)rW1[f*64 + 16*ct + c];
        f2[j] = (_Float16)rW2[f*64 + 16*ct + c];
      }
      B3[ct][ks] = f3; R1[ct][ks] = f1; R2[ct][ks] = f2;
    }
#pragma unroll
  for (int ct = 0; ct < 2; ++ct)
#pragma unroll
    for (int ks = 0; ks < 2; ++ks) {
      h16x8 f3;
#pragma unroll
      for (int j = 0; j < 8; ++j) {
        const int p = 32*ks + 8*q + j;
        const int f = 16*(p & 3) + (p >> 2);
        f3[j] = (_Float16)rW3[f*32 + 16*ct + c];
      }
      R3[ct][ks] = f3;
    }
  float b3s[4], rb1v[4], rb2v[4], rb3v[2];
#pragma unroll
  for (int ct = 0; ct < 4; ++ct) {
    b3s[ct]  = 32.f * pb3[16*ct + c];           // X = W3^T(sum relu) + 32*b3
    rb1v[ct] = rb1[16*ct + c];
    rb2v[ct] = rb2[16*ct + c];
  }
#pragma unroll
  for (int ct = 0; ct < 2; ++ct) rb3v[ct] = rb3[16*ct + c];

  // ---- X (C-layout, f32) -> permuted transpose -> A-layout
#pragma unroll
  for (int r = 0; r < 4; ++r) {
    h16x4 pk;
#pragma unroll
    for (int ct = 0; ct < 4; ++ct) pk[ct] = (_Float16)Xacc[ct][r];
    *(h16x4*)&h2T[4*q + r][4*c] = pk;
  }
  __builtin_amdgcn_s_waitcnt(0xC07F);
  __builtin_amdgcn_wave_barrier();
  h16x8 AX[2];
#pragma unroll
  for (int ks = 0; ks < 2; ++ks)
    AX[ks] = *(const h16x8*)&h2T[c][32*ks + 8*q];
  __builtin_amdgcn_wave_barrier();

  // ---- phi layer 3 (linear, pooled): rows = 16 states, all valid
  fx4 C3[4];
#pragma unroll
  for (int ct = 0; ct < 4; ++ct) {
    fx4 acc = {b3s[ct], b3s[ct], b3s[ct], b3s[ct]};
    acc = mfma16(AX[0], B3[ct][0], acc);
    acc = mfma16(AX[1], B3[ct][1], acc);
    C3[ct] = acc;
  }
#pragma unroll
  for (int r = 0; r < 4; ++r) {
    h16x4 pk;
#pragma unroll
    for (int ct = 0; ct < 4; ++ct) pk[ct] = (_Float16)C3[ct][r];
    *(h16x4*)&h2T[4*q + r][4*c] = pk;
  }
  __builtin_amdgcn_s_waitcnt(0xC07F);
  __builtin_amdgcn_wave_barrier();
  h16x8 A1r[2];
#pragma unroll
  for (int ks = 0; ks < 2; ++ks)
    A1r[ks] = *(const h16x8*)&h2T[c][32*ks + 8*q];
  __builtin_amdgcn_wave_barrier();

  // ---- rho layer 1
  fx4 D1[4];
#pragma unroll
  for (int ct = 0; ct < 4; ++ct) {
    fx4 acc = {rb1v[ct], rb1v[ct], rb1v[ct], rb1v[ct]};
    acc = mfma16(A1r[0], R1[ct][0], acc);
    acc = mfma16(A1r[1], R1[ct][1], acc);
    D1[ct] = acc;
  }
#pragma unroll
  for (int r = 0; r < 4; ++r) {
    h16x4 pk;
#pragma unroll
    for (int ct = 0; ct < 4; ++ct)
      pk[ct] = (_Float16)fmaxf(D1[ct][r], 0.f);
    *(h16x4*)&h2T[4*q + r][4*c] = pk;
  }
  __builtin_amdgcn_s_waitcnt(0xC07F);
  __builtin_amdgcn_wave_barrier();
  h16x8 A2r[2];
#pragma unroll
  for (int ks = 0; ks < 2; ++ks)
    A2r[ks] = *(const h16x8*)&h2T[c][32*ks + 8*q];
  __builtin_amdgcn_wave_barrier();

  // ---- rho layer 2
  fx4 D2[4];
#pragma unroll
  for (int ct = 0; ct < 4; ++ct) {
    fx4 acc = {rb2v[ct], rb2v[ct], rb2v[ct], rb2v[ct]};
    acc = mfma16(A2r[0], R2[ct][0], acc);
    acc = mfma16(A2r[1], R2[ct][1], acc);
    D2[ct] = acc;
  }
#pragma unroll
  for (int r = 0; r < 4; ++r) {
    h16x4 pk;
#pragma unroll
    for (int ct = 0; ct < 4; ++ct)
      pk[ct] = (_Float16)fmaxf(D2[ct][r], 0.f);
    *(h16x4*)&h2T[4*q + r][4*c] = pk;
  }
  __builtin_amdgcn_s_waitcnt(0xC07F);
  __builtin_amdgcn_wave_barrier();
  h16x8 A3r[2];
#pragma unroll
  for (int ks = 0; ks < 2; ++ks)
    A3r[ks] = *(const h16x8*)&h2T[c][32*ks + 8*q];
  __builtin_amdgcn_wave_barrier();

  // ---- rho layer 3 + store (all 16 rows valid)
  fx4 D3[2];
#pragma unroll
  for (int ct = 0; ct < 2; ++ct) {
    fx4 acc = {rb3v[ct], rb3v[ct], rb3v[ct], rb3v[ct]};
    acc = mfma16(A3r[0], R3[ct][0], acc);
    acc = mfma16(A3r[1], R3[ct][1], acc);
    D3[ct] = acc;
  }
  const int srow = sBase + 4*q;
#pragma unroll
  for (int ct = 0; ct < 2; ++ct)
#pragma unroll
    for (int r = 0; r < 4; ++r)
      out[(size_t)(srow + r)*32 + 16*ct + c] = D3[ct][r];
}

extern "C" void kernel_launch(void* const* d_in, const int* in_sizes, int n_in,
                              void* d_out, int out_size, void* d_ws, size_t ws_size,
                              hipStream_t stream) {
  const float* x   = (const float*)d_in[0];
  const float* vel = (const float*)d_in[1];
  const float* pW1 = (const float*)d_in[2];
  const float* pb1 = (const float*)d_in[3];
  const float* pW2 = (const float*)d_in[4];
  const float* pb2 = (const float*)d_in[5];
  const float* pW3 = (const float*)d_in[6];
  const float* pb3 = (const float*)d_in[7];
  const float* rW1 = (const float*)d_in[8];
  const float* rb1 = (const float*)d_in[9];
  const float* rW2 = (const float*)d_in[10];
  const float* rb2 = (const float*)d_in[11];
  const float* rW3 = (const float*)d_in[12];
  const float* rb3 = (const float*)d_in[13];
  float* out = (float*)d_out;

  const int B = in_sizes[0] / 64;        // x is [B, 64]
  deepset_main<<<dim3(B / 16), dim3(64), 0, stream>>>(
      x, vel, pW1, pb1, pW2, pb2, pW3, pb3,
      rW1, rb1, rW2, rb2, rW3, rb3, out);
}

// Round 6
// 127.021 us; speedup vs baseline: 2.2732x; 1.0552x over previous
//
#include <hip/hip_runtime.h>

typedef _Float16 h16x8 __attribute__((ext_vector_type(8)));
typedef _Float16 h16x4 __attribute__((ext_vector_type(4)));
typedef _Float16 h16x2 __attribute__((ext_vector_type(2)));
typedef float    fx4   __attribute__((ext_vector_type(4)));

static __device__ __forceinline__ fx4 mfma16(h16x8 a, h16x8 b, fx4 c) {
  return __builtin_amdgcn_mfma_f32_16x16x32_f16(a, b, c, 0, 0, 0);
}
static __device__ __forceinline__ h16x2 pkrtz(float a, float b) {
  auto r = __builtin_amdgcn_cvt_pkrtz(a, b);        // v_cvt_pkrtz_f16_f32
  h16x2 o; __builtin_memcpy(&o, &r, sizeof(o)); return o;
}
static __device__ __forceinline__ h16x2 splat2(float v) {
  const _Float16 h = (_Float16)v; h16x2 r; r[0] = h; r[1] = h; return r;
}
union ABfrag { h16x2 p[4]; h16x8 v; };
union H4     { h16x2 p[2]; h16x4 v; };

// State-major phi: MFMA rows = 16 states (lane c <-> state sBase+c), loop over
// 32 obstacles; pooling in registers. All weights from d_in (L2-served).
// __launch_bounds__(64,2): empirically the compiler caps VGPRs at 256/N for
// 1-wave blocks (N=4 -> 64, N=5 -> 48 => massive scratch spills, rounds 4/5).
// N=2 -> 128-VGPR cap, fits the ~100-reg live set, no spills.
// Tail weights are loaded per-stage (not all at once) to keep peak pressure
// under the cap and to overlap global-load latency with the LDS transposes.
//
// Transpose permutation: writer (lane c, col-tile ct) stores feature f=16*ct+c
// at position p=4*c+ct (one ds_write_b64); consumer weight rows are loaded at
// f = 16*(p&3)+(p>>2) so K-order matches (dot products are order-invariant).

__global__ __launch_bounds__(64, 2)
void deepset_main(const float* __restrict__ x,   const float* __restrict__ vel,
                  const float* __restrict__ pW1, const float* __restrict__ pb1,
                  const float* __restrict__ pW2, const float* __restrict__ pb2,
                  const float* __restrict__ pW3, const float* __restrict__ pb3,
                  const float* __restrict__ rW1, const float* __restrict__ rb1,
                  const float* __restrict__ rW2, const float* __restrict__ rb2,
                  const float* __restrict__ rW3, const float* __restrict__ rb3,
                  float* __restrict__ out)
{
  // one wave per block; everything wave-private, no __syncthreads anywhere
  __shared__ __align__(16) float    xT[16][68];   // 16 states x 64 floats (+pad)
  __shared__ __align__(16) _Float16 h2T[16][72];  // transpose buffer

  const int lane = threadIdx.x & 63;
  const int q    = lane >> 4;
  const int c    = lane & 15;
  const int sBase = blockIdx.x * 16;

  // ---- stage x tile into LDS (coalesced float4 loads)
  {
    const int s0 = lane >> 2, ch = lane & 3;
#pragma unroll
    for (int k = 0; k < 4; ++k) {
      const float4 g = ((const float4*)x)[(size_t)(sBase + s0)*16 + ch + 4*k];
      *(float4*)&xT[s0][(ch + 4*k)*4] = g;
    }
  }
  const float2 vc = *(const float2*)(vel + 2*(size_t)(sBase + c)); // lane's state

  // ---- layer-1 constants: lane's features f = 32*ks + 8*q + 2*t (+1);
  // vel-part folded in once per wave (f32 math, packed f16 store)
  h16x2 wx[2][4], wy[2][4], vbp[2][4];
#pragma unroll
  for (int ks = 0; ks < 2; ++ks)
#pragma unroll
    for (int t = 0; t < 4; ++t) {
      const int f0 = 32*ks + 8*q + 2*t;
      wx[ks][t] = pkrtz(pW1[f0], pW1[f0 + 1]);
      wy[ks][t] = pkrtz(pW1[64 + f0], pW1[64 + f0 + 1]);
      const float v0 = fmaf(vc.x, pW1[128 + f0],     fmaf(vc.y, pW1[192 + f0],     pb1[f0]));
      const float v1 = fmaf(vc.x, pW1[128 + f0 + 1], fmaf(vc.y, pW1[192 + f0 + 1], pb1[f0 + 1]));
      vbp[ks][t] = pkrtz(v0, v1);
    }

  // ---- phi W2 B-fragments (natural rows) + b2
  h16x8 B2[4][2];
#pragma unroll
  for (int ct = 0; ct < 4; ++ct)
#pragma unroll
    for (int ks = 0; ks < 2; ++ks) {
      ABfrag a;
#pragma unroll
      for (int t = 0; t < 4; ++t) {
        const int p0 = 32*ks + 8*q + 2*t;
        a.p[t] = pkrtz(pW2[p0*64 + 16*ct + c], pW2[(p0 + 1)*64 + 16*ct + c]);
      }
      B2[ct][ks] = a.v;
    }
  float b2v[4];
#pragma unroll
  for (int ct = 0; ct < 4; ++ct) b2v[ct] = pb2[16*ct + c];

  __builtin_amdgcn_s_waitcnt(0xC07F);          // lgkmcnt(0): xT staged
  __builtin_amdgcn_wave_barrier();

  const h16x2 z2 = splat2(0.f);
  float Xacc[4][4] = {};                        // X[feat 16ct+c][state 4q+r]

  // ================= phi + pool: 32 obstacles, LDS-fed, barrier-free ========
  float4 p_cur = *(const float4*)&xT[c][0];     // obstacles 0,1 of state c
#pragma unroll 1
  for (int oo = 0; oo < 16; ++oo) {
    float4 p_nxt;
    if (oo < 15) p_nxt = *(const float4*)&xT[c][4*(oo + 1)];
#pragma unroll
    for (int hh = 0; hh < 2; ++hh) {            // obstacle o = 2*oo + hh
      const h16x2 ox = splat2(hh ? p_cur.z : p_cur.x);
      const h16x2 oy = splat2(hh ? p_cur.w : p_cur.y);
      h16x8 A1[2];                              // h1[state=c][k=32ks+8q+j]
#pragma unroll
      for (int ks = 0; ks < 2; ++ks) {
        ABfrag a;
#pragma unroll
        for (int t = 0; t < 4; ++t) {
          const h16x2 h = ox * wx[ks][t] + oy * wy[ks][t] + vbp[ks][t];
          a.p[t] = __builtin_elementwise_max(h, z2);
        }
        A1[ks] = a.v;
      }
#pragma unroll
      for (int ct = 0; ct < 4; ++ct) {
        fx4 acc = {b2v[ct], b2v[ct], b2v[ct], b2v[ct]};   // bias as acc-init
        acc = mfma16(A1[0], B2[ct][0], acc);
        acc = mfma16(A1[1], B2[ct][1], acc);
#pragma unroll
        for (int r = 0; r < 4; ++r)
          Xacc[ct][r] += fmaxf(acc[r], 0.f);    // pool in registers
      }
    }
    p_cur = p_nxt;
  }

  // ---- X (C-layout f32) -> permuted transpose write
#pragma unroll
  for (int r = 0; r < 4; ++r) {
    H4 pk;
    pk.p[0] = pkrtz(Xacc[0][r], Xacc[1][r]);
    pk.p[1] = pkrtz(Xacc[2][r], Xacc[3][r]);
    *(h16x4*)&h2T[4*q + r][4*c] = pk.v;
  }

  // ---- phi W3 (permuted rows) loaded while the transpose round-trips
  h16x8 B3[4][2];
#pragma unroll
  for (int ct = 0; ct < 4; ++ct)
#pragma unroll
    for (int ks = 0; ks < 2; ++ks) {
      ABfrag a;
#pragma unroll
      for (int t = 0; t < 4; ++t) {
        const int p0 = 32*ks + 8*q + 2*t;
        const int f0 = 16*(p0 & 3) + (p0 >> 2);
        const int f1 = 16*((p0 + 1) & 3) + ((p0 + 1) >> 2);
        a.p[t] = pkrtz(pW3[f0*64 + 16*ct + c], pW3[f1*64 + 16*ct + c]);
      }
      B3[ct][ks] = a.v;
    }
  float b3s[4];
#pragma unroll
  for (int ct = 0; ct < 4; ++ct) b3s[ct] = 32.f * pb3[16*ct + c];

  __builtin_amdgcn_s_waitcnt(0xC07F);
  __builtin_amdgcn_wave_barrier();
  h16x8 AX[2];
#pragma unroll
  for (int ks = 0; ks < 2; ++ks)
    AX[ks] = *(const h16x8*)&h2T[c][32*ks + 8*q];
  __builtin_amdgcn_wave_barrier();

  // ---- phi layer 3 (linear, pooled): X = W3^T(sum relu) + 32*b3
  fx4 C3[4];
#pragma unroll
  for (int ct = 0; ct < 4; ++ct) {
    fx4 acc = {b3s[ct], b3s[ct], b3s[ct], b3s[ct]};
    acc = mfma16(AX[0], B3[ct][0], acc);
    acc = mfma16(AX[1], B3[ct][1], acc);
    C3[ct] = acc;
  }
#pragma unroll
  for (int r = 0; r < 4; ++r) {
    H4 pk;
    pk.p[0] = pkrtz(C3[0][r], C3[1][r]);
    pk.p[1] = pkrtz(C3[2][r], C3[3][r]);
    *(h16x4*)&h2T[4*q + r][4*c] = pk.v;
  }

  // ---- rho W1 (permuted rows) during the round-trip
  h16x8 R1[4][2];
#pragma unroll
  for (int ct = 0; ct < 4; ++ct)
#pragma unroll
    for (int ks = 0; ks < 2; ++ks) {
      ABfrag a;
#pragma unroll
      for (int t = 0; t < 4; ++t) {
        const int p0 = 32*ks + 8*q + 2*t;
        const int f0 = 16*(p0 & 3) + (p0 >> 2);
        const int f1 = 16*((p0 + 1) & 3) + ((p0 + 1) >> 2);
        a.p[t] = pkrtz(rW1[f0*64 + 16*ct + c], rW1[f1*64 + 16*ct + c]);
      }
      R1[ct][ks] = a.v;
    }
  float rb1v[4];
#pragma unroll
  for (int ct = 0; ct < 4; ++ct) rb1v[ct] = rb1[16*ct + c];

  __builtin_amdgcn_s_waitcnt(0xC07F);
  __builtin_amdgcn_wave_barrier();
  h16x8 A1r[2];
#pragma unroll
  for (int ks = 0; ks < 2; ++ks)
    A1r[ks] = *(const h16x8*)&h2T[c][32*ks + 8*q];
  __builtin_amdgcn_wave_barrier();

  // ---- rho layer 1
  fx4 D1[4];
#pragma unroll
  for (int ct = 0; ct < 4; ++ct) {
    fx4 acc = {rb1v[ct], rb1v[ct], rb1v[ct], rb1v[ct]};
    acc = mfma16(A1r[0], R1[ct][0], acc);
    acc = mfma16(A1r[1], R1[ct][1], acc);
    D1[ct] = acc;
  }
#pragma unroll
  for (int r = 0; r < 4; ++r) {
    H4 pk;
    pk.p[0] = pkrtz(fmaxf(D1[0][r], 0.f), fmaxf(D1[1][r], 0.f));
    pk.p[1] = pkrtz(fmaxf(D1[2][r], 0.f), fmaxf(D1[3][r], 0.f));
    *(h16x4*)&h2T[4*q + r][4*c] = pk.v;
  }

  // ---- rho W2 (permuted rows) during the round-trip
  h16x8 R2[4][2];
#pragma unroll
  for (int ct = 0; ct < 4; ++ct)
#pragma unroll
    for (int ks = 0; ks < 2; ++ks) {
      ABfrag a;
#pragma unroll
      for (int t = 0; t < 4; ++t) {
        const int p0 = 32*ks + 8*q + 2*t;
        const int f0 = 16*(p0 & 3) + (p0 >> 2);
        const int f1 = 16*((p0 + 1) & 3) + ((p0 + 1) >> 2);
        a.p[t] = pkrtz(rW2[f0*64 + 16*ct + c], rW2[f1*64 + 16*ct + c]);
      }
      R2[ct][ks] = a.v;
    }
  float rb2v[4];
#pragma unroll
  for (int ct = 0; ct < 4; ++ct) rb2v[ct] = rb2[16*ct + c];

  __builtin_amdgcn_s_waitcnt(0xC07F);
  __builtin_amdgcn_wave_barrier();
  h16x8 A2r[2];
#pragma unroll
  for (int ks = 0; ks < 2; ++ks)
    A2r[ks] = *(const h16x8*)&h2T[c][32*ks + 8*q];
  __builtin_amdgcn_wave_barrier();

  // ---- rho layer 2
  fx4 D2[4];
#pragma unroll
  for (int ct = 0; ct < 4; ++ct) {
    fx4 acc = {rb2v[ct], rb2v[ct], rb2v[ct], rb2v[ct]};
    acc = mfma16(A2r[0], R2[ct][0], acc);
    acc = mfma16(A2r[1], R2[ct][1], acc);
    D2[ct] = acc;
  }
#pragma unroll
  for (int r = 0; r < 4; ++r) {
    H4 pk;
    pk.p[0] = pkrtz(fmaxf(D2[0][r], 0.f), fmaxf(D2[1][r], 0.f));
    pk.p[1] = pkrtz(fmaxf(D2[2][r], 0.f), fmaxf(D2[3][r], 0.f));
    *(h16x4*)&h2T[4*q + r][4*c] = pk.v;
  }

  // ---- rho W3 (permuted rows) during the round-trip
  h16x8 R3[2][2];
#pragma unroll
  for (int ct = 0; ct < 2; ++ct)
#pragma unroll
    for (int ks = 0; ks < 2; ++ks) {
      ABfrag a;
#pragma unroll
      for (int t = 0; t < 4; ++t) {
        const int p0 = 32*ks + 8*q + 2*t;
        const int f0 = 16*(p0 & 3) + (p0 >> 2);
        const int f1 = 16*((p0 + 1) & 3) + ((p0 + 1) >> 2);
        a.p[t] = pkrtz(rW3[f0*32 + 16*ct + c], rW3[f1*32 + 16*ct + c]);
      }
      R3[ct][ks] = a.v;
    }
  float rb3v[2];
#pragma unroll
  for (int ct = 0; ct < 2; ++ct) rb3v[ct] = rb3[16*ct + c];

  __builtin_amdgcn_s_waitcnt(0xC07F);
  __builtin_amdgcn_wave_barrier();
  h16x8 A3r[2];
#pragma unroll
  for (int ks = 0; ks < 2; ++ks)
    A3r[ks] = *(const h16x8*)&h2T[c][32*ks + 8*q];
  __builtin_amdgcn_wave_barrier();

  // ---- rho layer 3 + store (all 16 rows valid)
  fx4 D3[2];
#pragma unroll
  for (int ct = 0; ct < 2; ++ct) {
    fx4 acc = {rb3v[ct], rb3v[ct], rb3v[ct], rb3v[ct]};
    acc = mfma16(A3r[0], R3[ct][0], acc);
    acc = mfma16(A3r[1], R3[ct][1], acc);
    D3[ct] = acc;
  }
  const int srow = sBase + 4*q;
#pragma unroll
  for (int ct = 0; ct < 2; ++ct)
#pragma unroll
    for (int r = 0; r < 4; ++r)
      out[(size_t)(srow + r)*32 + 16*ct + c] = D3[ct][r];
}

extern "C" void kernel_launch(void* const* d_in, const int* in_sizes, int n_in,
                              void* d_out, int out_size, void* d_ws, size_t ws_size,
                              hipStream_t stream) {
  const float* x   = (const float*)d_in[0];
  const float* vel = (const float*)d_in[1];
  const float* pW1 = (const float*)d_in[2];
  const float* pb1 = (const float*)d_in[3];
  const float* pW2 = (const float*)d_in[4];
  const float* pb2 = (const float*)d_in[5];
  const float* pW3 = (const float*)d_in[6];
  const float* pb3 = (const float*)d_in[7];
  const float* rW1 = (const float*)d_in[8];
  const float* rb1 = (const float*)d_in[9];
  const float* rW2 = (const float*)d_in[10];
  const float* rb2 = (const float*)d_in[11];
  const float* rW3 = (const float*)d_in[12];
  const float* rb3 = (const float*)d_in[13];
  float* out = (float*)d_out;

  const int B = in_sizes[0] / 64;        // x is [B, 64]
  deepset_main<<<dim3(B / 16), dim3(64), 0, stream>>>(
      x, vel, pW1, pb1, pW2, pb2, pW3, pb3,
      rW1, rb1, rW2, rb2, rW3, rb3, out);
}

// Round 7
// 121.675 us; speedup vs baseline: 2.3731x; 1.0439x over previous
//
#include <hip/hip_runtime.h>

typedef _Float16 h16x8 __attribute__((ext_vector_type(8)));
typedef _Float16 h16x4 __attribute__((ext_vector_type(4)));
typedef _Float16 h16x2 __attribute__((ext_vector_type(2)));
typedef float    fx4   __attribute__((ext_vector_type(4)));

static __device__ __forceinline__ fx4 mfma16(h16x8 a, h16x8 b, fx4 c) {
  return __builtin_amdgcn_mfma_f32_16x16x32_f16(a, b, c, 0, 0, 0);
}
static __device__ __forceinline__ h16x2 pkrtz(float a, float b) {
  auto r = __builtin_amdgcn_cvt_pkrtz(a, b);        // v_cvt_pkrtz_f16_f32
  h16x2 o; __builtin_memcpy(&o, &r, sizeof(o)); return o;
}
union ABfrag { h16x2 p[4]; h16x8 v; };
union H4     { h16x2 p[2]; h16x4 v; };

// Block-shared LDS weight tiles (round-7 move): 8 waves share one cooperative
// staging pass — coalesced float4 global reads, f16 transposed store
// tile[col][row] (stride 72 halves = 144 B: 16B-aligned rows, 2-way-max read
// conflicts). A lane's MFMA B-fragment = ONE ds_read_b128 (8 contiguous
// K-positions of its column) instead of 8 scalar global loads. Matrices that
// consume transposed activations are staged with permuted rows
// f(p) = 16*(p&3)+(p>>2) so fragment reads stay contiguous.
// Per-wave xh tile holds x (f16) during phi, then is reused as the transpose
// buffer (wave-private, no cross-wave hazard). One __syncthreads total.
// Weights come from d_in (L2-served); d_ws is uncached (round-4 lesson);
// 1-wave blocks' 256/N VGPR cap caused round-5 spills (launch_bounds 512,4
// -> 128-reg cap, ~100 live).

__global__ __launch_bounds__(512, 4)
void deepset_main(const float* __restrict__ x,   const float* __restrict__ vel,
                  const float* __restrict__ pW1, const float* __restrict__ pb1,
                  const float* __restrict__ pW2, const float* __restrict__ pb2,
                  const float* __restrict__ pW3, const float* __restrict__ pb3,
                  const float* __restrict__ rW1, const float* __restrict__ rb1,
                  const float* __restrict__ rW2, const float* __restrict__ rb2,
                  const float* __restrict__ rW3, const float* __restrict__ rb3,
                  float* __restrict__ out)
{
  __shared__ __align__(16) _Float16 L2T[64][72];   // phi W2, natural rows
  __shared__ __align__(16) _Float16 L3T[64][72];   // phi W3, permuted rows
  __shared__ __align__(16) _Float16 Q1T[64][72];   // rho W1, permuted rows
  __shared__ __align__(16) _Float16 Q2T[64][72];   // rho W2, permuted rows
  __shared__ __align__(16) _Float16 Q3T[32][72];   // rho W3, permuted rows
  __shared__ __align__(16) _Float16 xh[8][16][72]; // per-wave x tile / transpose buf

  const int tid  = threadIdx.x;
  const int wave = tid >> 6;
  const int lane = tid & 63;
  const int q    = lane >> 4;
  const int c    = lane & 15;
  const int sBase = blockIdx.x * 128;
  const int sWave = sBase + wave * 16;

  // ---- cooperative weight staging: 512 threads, coalesced reads
  {
    const int p  = tid >> 3;               // source K-position (row in tile)
    const int cg = (tid & 7) * 8;          // 8-column group
    const int f  = 16*(p & 3) + (p >> 2);  // permuted source row
    const fx4 w2a = *(const fx4*)(pW2 + p*64 + cg);
    const fx4 w2b = *(const fx4*)(pW2 + p*64 + cg + 4);
    const fx4 w3a = *(const fx4*)(pW3 + f*64 + cg);
    const fx4 w3b = *(const fx4*)(pW3 + f*64 + cg + 4);
    const fx4 r1a = *(const fx4*)(rW1 + f*64 + cg);
    const fx4 r1b = *(const fx4*)(rW1 + f*64 + cg + 4);
    const fx4 r2a = *(const fx4*)(rW2 + f*64 + cg);
    const fx4 r2b = *(const fx4*)(rW2 + f*64 + cg + 4);
#pragma unroll
    for (int i = 0; i < 4; ++i) {
      L2T[cg + i][p]     = (_Float16)w2a[i];
      L2T[cg + 4 + i][p] = (_Float16)w2b[i];
      L3T[cg + i][p]     = (_Float16)w3a[i];
      L3T[cg + 4 + i][p] = (_Float16)w3b[i];
      Q1T[cg + i][p]     = (_Float16)r1a[i];
      Q1T[cg + 4 + i][p] = (_Float16)r1b[i];
      Q2T[cg + i][p]     = (_Float16)r2a[i];
      Q2T[cg + 4 + i][p] = (_Float16)r2b[i];
    }
    if (tid < 256) {                       // rho W3 is 64x32
      const int p3  = tid >> 2;
      const int cg3 = (tid & 3) * 8;
      const int f3  = 16*(p3 & 3) + (p3 >> 2);
      const fx4 r3a = *(const fx4*)(rW3 + f3*32 + cg3);
      const fx4 r3b = *(const fx4*)(rW3 + f3*32 + cg3 + 4);
#pragma unroll
      for (int i = 0; i < 4; ++i) {
        Q3T[cg3 + i][p3]     = (_Float16)r3a[i];
        Q3T[cg3 + 4 + i][p3] = (_Float16)r3b[i];
      }
    }
  }

  // ---- x tile -> per-wave LDS (f16; pkrtz at staging)
  {
    const int s0 = lane >> 2, ch = (lane & 3) * 16;
#pragma unroll
    for (int k = 0; k < 4; ++k) {
      const fx4 g = *(const fx4*)(x + (size_t)(sWave + s0)*64 + ch + 4*k);
      H4 pk; pk.p[0] = pkrtz(g[0], g[1]); pk.p[1] = pkrtz(g[2], g[3]);
      *(h16x4*)&xh[wave][s0][ch + 4*k] = pk.v;
    }
  }
  const float2 vc = *(const float2*)(vel + 2*(size_t)(sWave + c)); // lane's state

  // ---- layer-1 constants (1.3 KB, same for all waves -> L2-hot)
  h16x2 wx[2][4], wy[2][4], vbp[2][4];
#pragma unroll
  for (int ks = 0; ks < 2; ++ks)
#pragma unroll
    for (int t = 0; t < 4; ++t) {
      const int f0 = 32*ks + 8*q + 2*t;
      wx[ks][t] = pkrtz(pW1[f0], pW1[f0 + 1]);
      wy[ks][t] = pkrtz(pW1[64 + f0], pW1[64 + f0 + 1]);
      const float v0 = fmaf(vc.x, pW1[128 + f0],     fmaf(vc.y, pW1[192 + f0],     pb1[f0]));
      const float v1 = fmaf(vc.x, pW1[128 + f0 + 1], fmaf(vc.y, pW1[192 + f0 + 1], pb1[f0 + 1]));
      vbp[ks][t] = pkrtz(v0, v1);
    }
  float b2v[4];
#pragma unroll
  for (int ct = 0; ct < 4; ++ct) b2v[ct] = pb2[16*ct + c];

  __syncthreads();                         // weight tiles + x tiles ready

  // ---- phi W2 B-fragments: one ds_read_b128 each
  h16x8 B2[4][2];
#pragma unroll
  for (int ct = 0; ct < 4; ++ct)
#pragma unroll
    for (int ks = 0; ks < 2; ++ks)
      B2[ct][ks] = *(const h16x8*)&L2T[16*ct + c][32*ks + 8*q];

  const h16x2 z2 = {(_Float16)0.f, (_Float16)0.f};
  const fx4 zf4 = {0.f, 0.f, 0.f, 0.f};
  fx4 Xacc[4] = {zf4, zf4, zf4, zf4};      // X[feat 16ct+c][state 4q+r]

  // ================= phi + pool: 32 obstacles, LDS-fed, barrier-free ========
  h16x4 p_cur = *(const h16x4*)&xh[wave][c][0];
#pragma unroll 1
  for (int oo = 0; oo < 16; ++oo) {
    h16x4 p_nxt;
    if (oo < 15) p_nxt = *(const h16x4*)&xh[wave][c][4*(oo + 1)];
#pragma unroll
    for (int hh = 0; hh < 2; ++hh) {       // obstacle 2*oo + hh of state c
      h16x2 ox, oy;
      ox[0] = p_cur[2*hh];     ox[1] = p_cur[2*hh];
      oy[0] = p_cur[2*hh + 1]; oy[1] = p_cur[2*hh + 1];
      h16x8 A1[2];                         // h1[state=c][k=32ks+8q+j]
#pragma unroll
      for (int ks = 0; ks < 2; ++ks) {
        ABfrag a;
#pragma unroll
        for (int t = 0; t < 4; ++t) {
          const h16x2 h = ox * wx[ks][t] + oy * wy[ks][t] + vbp[ks][t];
          a.p[t] = __builtin_elementwise_max(h, z2);
        }
        A1[ks] = a.v;
      }
#pragma unroll
      for (int ct = 0; ct < 4; ++ct) {
        fx4 acc = {b2v[ct], b2v[ct], b2v[ct], b2v[ct]};   // bias as acc-init
        acc = mfma16(A1[0], B2[ct][0], acc);
        acc = mfma16(A1[1], B2[ct][1], acc);
        Xacc[ct] += __builtin_elementwise_max(acc, zf4);  // relu-pool (pk f32)
      }
    }
    p_cur = p_nxt;
  }

  // ---- tail: reuse this wave's xh tile as the transpose buffer
  _Float16 (*h2T)[72] = xh[wave];

  // X (C-layout f32) -> permuted transpose write
#pragma unroll
  for (int r = 0; r < 4; ++r) {
    H4 pk;
    pk.p[0] = pkrtz(Xacc[0][r], Xacc[1][r]);
    pk.p[1] = pkrtz(Xacc[2][r], Xacc[3][r]);
    *(h16x4*)&h2T[4*q + r][4*c] = pk.v;
  }
  // phi W3 fragments (permuted rows already staged)
  h16x8 B3[4][2];
#pragma unroll
  for (int ct = 0; ct < 4; ++ct)
#pragma unroll
    for (int ks = 0; ks < 2; ++ks)
      B3[ct][ks] = *(const h16x8*)&L3T[16*ct + c][32*ks + 8*q];
  float b3s[4];
#pragma unroll
  for (int ct = 0; ct < 4; ++ct) b3s[ct] = 32.f * pb3[16*ct + c];

  __builtin_amdgcn_s_waitcnt(0xC07F);      // lgkmcnt(0)
  __builtin_amdgcn_wave_barrier();
  h16x8 AX[2];
#pragma unroll
  for (int ks = 0; ks < 2; ++ks)
    AX[ks] = *(const h16x8*)&h2T[c][32*ks + 8*q];
  __builtin_amdgcn_wave_barrier();

  // phi layer 3 (linear, pooled): X = W3^T(sum relu) + 32*b3
  fx4 C3[4];
#pragma unroll
  for (int ct = 0; ct < 4; ++ct) {
    fx4 acc = {b3s[ct], b3s[ct], b3s[ct], b3s[ct]};
    acc = mfma16(AX[0], B3[ct][0], acc);
    acc = mfma16(AX[1], B3[ct][1], acc);
    C3[ct] = acc;
  }
#pragma unroll
  for (int r = 0; r < 4; ++r) {
    H4 pk;
    pk.p[0] = pkrtz(C3[0][r], C3[1][r]);
    pk.p[1] = pkrtz(C3[2][r], C3[3][r]);
    *(h16x4*)&h2T[4*q + r][4*c] = pk.v;
  }
  h16x8 R1[4][2];
#pragma unroll
  for (int ct = 0; ct < 4; ++ct)
#pragma unroll
    for (int ks = 0; ks < 2; ++ks)
      R1[ct][ks] = *(const h16x8*)&Q1T[16*ct + c][32*ks + 8*q];
  float rb1v[4];
#pragma unroll
  for (int ct = 0; ct < 4; ++ct) rb1v[ct] = rb1[16*ct + c];

  __builtin_amdgcn_s_waitcnt(0xC07F);
  __builtin_amdgcn_wave_barrier();
  h16x8 A1r[2];
#pragma unroll
  for (int ks = 0; ks < 2; ++ks)
    A1r[ks] = *(const h16x8*)&h2T[c][32*ks + 8*q];
  __builtin_amdgcn_wave_barrier();

  // rho layer 1
  fx4 D1[4];
#pragma unroll
  for (int ct = 0; ct < 4; ++ct) {
    fx4 acc = {rb1v[ct], rb1v[ct], rb1v[ct], rb1v[ct]};
    acc = mfma16(A1r[0], R1[ct][0], acc);
    acc = mfma16(A1r[1], R1[ct][1], acc);
    D1[ct] = __builtin_elementwise_max(acc, zf4);
  }
#pragma unroll
  for (int r = 0; r < 4; ++r) {
    H4 pk;
    pk.p[0] = pkrtz(D1[0][r], D1[1][r]);
    pk.p[1] = pkrtz(D1[2][r], D1[3][r]);
    *(h16x4*)&h2T[4*q + r][4*c] = pk.v;
  }
  h16x8 R2[4][2];
#pragma unroll
  for (int ct = 0; ct < 4; ++ct)
#pragma unroll
    for (int ks = 0; ks < 2; ++ks)
      R2[ct][ks] = *(const h16x8*)&Q2T[16*ct + c][32*ks + 8*q];
  float rb2v[4];
#pragma unroll
  for (int ct = 0; ct < 4; ++ct) rb2v[ct] = rb2[16*ct + c];

  __builtin_amdgcn_s_waitcnt(0xC07F);
  __builtin_amdgcn_wave_barrier();
  h16x8 A2r[2];
#pragma unroll
  for (int ks = 0; ks < 2; ++ks)
    A2r[ks] = *(const h16x8*)&h2T[c][32*ks + 8*q];
  __builtin_amdgcn_wave_barrier();

  // rho layer 2
  fx4 D2[4];
#pragma unroll
  for (int ct = 0; ct < 4; ++ct) {
    fx4 acc = {rb2v[ct], rb2v[ct], rb2v[ct], rb2v[ct]};
    acc = mfma16(A2r[0], R2[ct][0], acc);
    acc = mfma16(A2r[1], R2[ct][1], acc);
    D2[ct] = __builtin_elementwise_max(acc, zf4);
  }
#pragma unroll
  for (int r = 0; r < 4; ++r) {
    H4 pk;
    pk.p[0] = pkrtz(D2[0][r], D2[1][r]);
    pk.p[1] = pkrtz(D2[2][r], D2[3][r]);
    *(h16x4*)&h2T[4*q + r][4*c] = pk.v;
  }
  h16x8 R3[2][2];
#pragma unroll
  for (int ct = 0; ct < 2; ++ct)
#pragma unroll
    for (int ks = 0; ks < 2; ++ks)
      R3[ct][ks] = *(const h16x8*)&Q3T[16*ct + c][32*ks + 8*q];
  float rb3v[2];
#pragma unroll
  for (int ct = 0; ct < 2; ++ct) rb3v[ct] = rb3[16*ct + c];

  __builtin_amdgcn_s_waitcnt(0xC07F);
  __builtin_amdgcn_wave_barrier();
  h16x8 A3r[2];
#pragma unroll
  for (int ks = 0; ks < 2; ++ks)
    A3r[ks] = *(const h16x8*)&h2T[c][32*ks + 8*q];
  __builtin_amdgcn_wave_barrier();

  // rho layer 3 + store
  fx4 D3[2];
#pragma unroll
  for (int ct = 0; ct < 2; ++ct) {
    fx4 acc = {rb3v[ct], rb3v[ct], rb3v[ct], rb3v[ct]};
    acc = mfma16(A3r[0], R3[ct][0], acc);
    acc = mfma16(A3r[1], R3[ct][1], acc);
    D3[ct] = acc;
  }
  const int srow = sWave + 4*q;
#pragma unroll
  for (int ct = 0; ct < 2; ++ct)
#pragma unroll
    for (int r = 0; r < 4; ++r)
      out[(size_t)(srow + r)*32 + 16*ct + c] = D3[ct][r];
}

extern "C" void kernel_launch(void* const* d_in, const int* in_sizes, int n_in,
                              void* d_out, int out_size, void* d_ws, size_t ws_size,
                              hipStream_t stream) {
  const float* x   = (const float*)d_in[0];
  const float* vel = (const float*)d_in[1];
  const float* pW1 = (const float*)d_in[2];
  const float* pb1 = (const float*)d_in[3];
  const float* pW2 = (const float*)d_in[4];
  const float* pb2 = (const float*)d_in[5];
  const float* pW3 = (const float*)d_in[6];
  const float* pb3 = (const float*)d_in[7];
  const float* rW1 = (const float*)d_in[8];
  const float* rb1 = (const float*)d_in[9];
  const float* rW2 = (const float*)d_in[10];
  const float* rb2 = (const float*)d_in[11];
  const float* rW3 = (const float*)d_in[12];
  const float* rb3 = (const float*)d_in[13];
  float* out = (float*)d_out;

  const int B = in_sizes[0] / 64;        // x is [B, 64]
  deepset_main<<<dim3(B / 128), dim3(512), 0, stream>>>(
      x, vel, pW1, pb1, pW2, pb2, pW3, pb3,
      rW1, rb1, rW2, rb2, rW3, rb3, out);
}

// Round 8
// 113.781 us; speedup vs baseline: 2.5377x; 1.0694x over previous
//
#include <hip/hip_runtime.h>

typedef _Float16 h16x8 __attribute__((ext_vector_type(8)));
typedef _Float16 h16x4 __attribute__((ext_vector_type(4)));
typedef _Float16 h16x2 __attribute__((ext_vector_type(2)));
typedef float    fx4   __attribute__((ext_vector_type(4)));

static __device__ __forceinline__ fx4 mfma16(h16x8 a, h16x8 b, fx4 c) {
  return __builtin_amdgcn_mfma_f32_16x16x32_f16(a, b, c, 0, 0, 0);
}
static __device__ __forceinline__ h16x2 pkrtz(float a, float b) {
  auto r = __builtin_amdgcn_cvt_pkrtz(a, b);        // v_cvt_pkrtz_f16_f32
  h16x2 o; __builtin_memcpy(&o, &r, sizeof(o)); return o;
}
union ABfrag { h16x2 p[4]; h16x8 v; };
union H4     { h16x2 p[2]; h16x4 v; };

// R8: phi loop is VALU-pipe-bound (R6->R7 showed weight prep was minor; the
// ~70 VALU inst per 8 MFMA caps MfmaUtil at ~33%). Cuts here:
//  - f16 packed pooling: pkrtz + pk_max_f16 + pk_add_f16 = 8 inst/hh (was 16
//    f32 ops); accumulation error ~0.1 << 1.19 threshold.
//  - branch-free obstacle prefetch (wrapped index).
//  - staging rewrite: coalesced row loads + ONE ds_write_b128 per thread per
//    matrix (was 8x ds_write_b16 at 16-way bank conflict).
// Retained lessons: weights from d_in (d_ws uncached, R4); launch_bounds caps
// VGPR at threads_per_block/64*64... (512,4) -> 128-reg cap, no spills (R5/R6);
// 16 waves/CU occupancy ceiling given ~100 VGPR live set.
//
// Transpose permutation: writer (lane c, col-tile ct) stores feature f=16*ct+c
// at position p=4*c+ct (one ds_write_b64); consumer weight rows are staged at
// f = 16*(p&3)+(p>>2) so K-order matches (dot products are order-invariant).

__global__ __launch_bounds__(512, 4)
void deepset_main(const float* __restrict__ x,   const float* __restrict__ vel,
                  const float* __restrict__ pW1, const float* __restrict__ pb1,
                  const float* __restrict__ pW2, const float* __restrict__ pb2,
                  const float* __restrict__ pW3, const float* __restrict__ pb3,
                  const float* __restrict__ rW1, const float* __restrict__ rb1,
                  const float* __restrict__ rW2, const float* __restrict__ rb2,
                  const float* __restrict__ rW3, const float* __restrict__ rb3,
                  float* __restrict__ out)
{
  __shared__ __align__(16) _Float16 L2T[64][72];   // phi W2, natural rows
  __shared__ __align__(16) _Float16 L3T[64][72];   // phi W3, permuted rows
  __shared__ __align__(16) _Float16 Q1T[64][72];   // rho W1, permuted rows
  __shared__ __align__(16) _Float16 Q2T[64][72];   // rho W2, permuted rows
  __shared__ __align__(16) _Float16 Q3T[32][72];   // rho W3, permuted rows
  __shared__ __align__(16) _Float16 xh[8][16][72]; // per-wave x tile / transpose buf

  const int tid  = threadIdx.x;
  const int wave = tid >> 6;
  const int lane = tid & 63;
  const int q    = lane >> 4;
  const int c    = lane & 15;
  const int sBase = blockIdx.x * 128;
  const int sWave = sBase + wave * 16;

  // ---- cooperative weight staging: coalesced row loads, b128 LDS writes.
  // thread -> column col=tid&63, k-group kg=tid>>6 (positions p=8kg..8kg+7).
  {
    const int col = tid & 63;
    const int kg  = tid >> 6;
    float v2[8], v3[8], r1[8], r2[8];
#pragma unroll
    for (int j = 0; j < 8; ++j) {
      const int p = 8*kg + j;
      const int f = 16*(p & 3) + (p >> 2);         // permuted source row
      v2[j] = pW2[p*64 + col];
      v3[j] = pW3[f*64 + col];
      r1[j] = rW1[f*64 + col];
      r2[j] = rW2[f*64 + col];
    }
    h16x8 h2v, h3v, h1v, h2r;
#pragma unroll
    for (int j = 0; j < 8; ++j) { h2v[j] = (_Float16)v2[j]; h3v[j] = (_Float16)v3[j];
                                  h1v[j] = (_Float16)r1[j]; h2r[j] = (_Float16)r2[j]; }
    *(h16x8*)&L2T[col][8*kg] = h2v;
    *(h16x8*)&L3T[col][8*kg] = h3v;
    *(h16x8*)&Q1T[col][8*kg] = h1v;
    *(h16x8*)&Q2T[col][8*kg] = h2r;
    if (tid < 256) {                               // rho W3 is 64x32
      const int col3 = tid & 31;
      const int kg3  = tid >> 5;
      float r3[8];
#pragma unroll
      for (int j = 0; j < 8; ++j) {
        const int p = 8*kg3 + j;
        const int f = 16*(p & 3) + (p >> 2);
        r3[j] = rW3[f*32 + col3];
      }
      h16x8 h3r;
#pragma unroll
      for (int j = 0; j < 8; ++j) h3r[j] = (_Float16)r3[j];
      *(h16x8*)&Q3T[col3][8*kg3] = h3r;
    }
  }

  // ---- x tile -> per-wave LDS (f16)
  {
    const int s0 = lane >> 2, ch = (lane & 3) * 16;
#pragma unroll
    for (int k = 0; k < 4; ++k) {
      const fx4 g = *(const fx4*)(x + (size_t)(sWave + s0)*64 + ch + 4*k);
      H4 pk; pk.p[0] = pkrtz(g[0], g[1]); pk.p[1] = pkrtz(g[2], g[3]);
      *(h16x4*)&xh[wave][s0][ch + 4*k] = pk.v;
    }
  }
  const float2 vc = *(const float2*)(vel + 2*(size_t)(sWave + c)); // lane's state

  // ---- layer-1 constants (same for all waves -> L2-hot)
  h16x2 wx[2][4], wy[2][4], vbp[2][4];
#pragma unroll
  for (int ks = 0; ks < 2; ++ks)
#pragma unroll
    for (int t = 0; t < 4; ++t) {
      const int f0 = 32*ks + 8*q + 2*t;
      wx[ks][t] = pkrtz(pW1[f0], pW1[f0 + 1]);
      wy[ks][t] = pkrtz(pW1[64 + f0], pW1[64 + f0 + 1]);
      const float v0 = fmaf(vc.x, pW1[128 + f0],     fmaf(vc.y, pW1[192 + f0],     pb1[f0]));
      const float v1 = fmaf(vc.x, pW1[128 + f0 + 1], fmaf(vc.y, pW1[192 + f0 + 1], pb1[f0 + 1]));
      vbp[ks][t] = pkrtz(v0, v1);
    }
  float b2v[4];
#pragma unroll
  for (int ct = 0; ct < 4; ++ct) b2v[ct] = pb2[16*ct + c];

  __syncthreads();                         // weight tiles + x tiles ready

  // ---- phi W2 B-fragments: one ds_read_b128 each
  h16x8 B2[4][2];
#pragma unroll
  for (int ct = 0; ct < 4; ++ct)
#pragma unroll
    for (int ks = 0; ks < 2; ++ks)
      B2[ct][ks] = *(const h16x8*)&L2T[16*ct + c][32*ks + 8*q];

  const h16x2 z2 = {(_Float16)0.f, (_Float16)0.f};
  h16x2 Xh[4][2] = {{z2, z2}, {z2, z2}, {z2, z2}, {z2, z2}};  // f16 pooled X

  // ================= phi + pool: 32 obstacles, LDS-fed, barrier-free ========
  h16x4 p_cur = *(const h16x4*)&xh[wave][c][0];
#pragma unroll 1
  for (int oo = 0; oo < 16; ++oo) {
    // branch-free prefetch (wrap at 16; last value unused)
    h16x4 p_nxt = *(const h16x4*)&xh[wave][c][4*((oo + 1) & 15)];
#pragma unroll
    for (int hh = 0; hh < 2; ++hh) {       // obstacle 2*oo + hh of state c
      h16x2 ox, oy;
      ox[0] = p_cur[2*hh];     ox[1] = p_cur[2*hh];
      oy[0] = p_cur[2*hh + 1]; oy[1] = p_cur[2*hh + 1];
      h16x8 A1[2];                         // h1[state=c][k=32ks+8q+j]
#pragma unroll
      for (int ks = 0; ks < 2; ++ks) {
        ABfrag a;
#pragma unroll
        for (int t = 0; t < 4; ++t) {
          const h16x2 h = ox * wx[ks][t] + oy * wy[ks][t] + vbp[ks][t];
          a.p[t] = __builtin_elementwise_max(h, z2);
        }
        A1[ks] = a.v;
      }
#pragma unroll
      for (int ct = 0; ct < 4; ++ct) {
        fx4 acc = {b2v[ct], b2v[ct], b2v[ct], b2v[ct]};   // bias as acc-init
        acc = mfma16(A1[0], B2[ct][0], acc);
        acc = mfma16(A1[1], B2[ct][1], acc);
        // f16 packed relu-pool: 2 pkrtz + pk_max + pk_add per ct
        const h16x2 lo = pkrtz(acc[0], acc[1]);
        const h16x2 hi = pkrtz(acc[2], acc[3]);
        Xh[ct][0] += __builtin_elementwise_max(lo, z2);
        Xh[ct][1] += __builtin_elementwise_max(hi, z2);
      }
    }
    p_cur = p_nxt;
  }

  // ---- tail: reuse this wave's xh tile as the transpose buffer
  _Float16 (*h2T)[72] = xh[wave];

  // X (f16 pairs) -> permuted transpose write
#pragma unroll
  for (int r = 0; r < 4; ++r) {
    h16x4 pk;
#pragma unroll
    for (int ct = 0; ct < 4; ++ct) pk[ct] = Xh[ct][r >> 1][r & 1];
    *(h16x4*)&h2T[4*q + r][4*c] = pk;
  }
  // phi W3 fragments (permuted rows already staged)
  h16x8 B3[4][2];
#pragma unroll
  for (int ct = 0; ct < 4; ++ct)
#pragma unroll
    for (int ks = 0; ks < 2; ++ks)
      B3[ct][ks] = *(const h16x8*)&L3T[16*ct + c][32*ks + 8*q];
  float b3s[4];
#pragma unroll
  for (int ct = 0; ct < 4; ++ct) b3s[ct] = 32.f * pb3[16*ct + c];

  __builtin_amdgcn_s_waitcnt(0xC07F);      // lgkmcnt(0)
  __builtin_amdgcn_wave_barrier();
  h16x8 AX[2];
#pragma unroll
  for (int ks = 0; ks < 2; ++ks)
    AX[ks] = *(const h16x8*)&h2T[c][32*ks + 8*q];
  __builtin_amdgcn_wave_barrier();

  // phi layer 3 (linear, pooled): X = W3^T(sum relu) + 32*b3
  fx4 C3[4];
#pragma unroll
  for (int ct = 0; ct < 4; ++ct) {
    fx4 acc = {b3s[ct], b3s[ct], b3s[ct], b3s[ct]};
    acc = mfma16(AX[0], B3[ct][0], acc);
    acc = mfma16(AX[1], B3[ct][1], acc);
    C3[ct] = acc;
  }
#pragma unroll
  for (int r = 0; r < 4; ++r) {
    H4 pk;
    pk.p[0] = pkrtz(C3[0][r], C3[1][r]);
    pk.p[1] = pkrtz(C3[2][r], C3[3][r]);
    *(h16x4*)&h2T[4*q + r][4*c] = pk.v;
  }
  h16x8 R1[4][2];
#pragma unroll
  for (int ct = 0; ct < 4; ++ct)
#pragma unroll
    for (int ks = 0; ks < 2; ++ks)
      R1[ct][ks] = *(const h16x8*)&Q1T[16*ct + c][32*ks + 8*q];
  float rb1v[4];
#pragma unroll
  for (int ct = 0; ct < 4; ++ct) rb1v[ct] = rb1[16*ct + c];

  __builtin_amdgcn_s_waitcnt(0xC07F);
  __builtin_amdgcn_wave_barrier();
  h16x8 A1r[2];
#pragma unroll
  for (int ks = 0; ks < 2; ++ks)
    A1r[ks] = *(const h16x8*)&h2T[c][32*ks + 8*q];
  __builtin_amdgcn_wave_barrier();

  // rho layer 1
  const fx4 zf4 = {0.f, 0.f, 0.f, 0.f};
  fx4 D1[4];
#pragma unroll
  for (int ct = 0; ct < 4; ++ct) {
    fx4 acc = {rb1v[ct], rb1v[ct], rb1v[ct], rb1v[ct]};
    acc = mfma16(A1r[0], R1[ct][0], acc);
    acc = mfma16(A1r[1], R1[ct][1], acc);
    D1[ct] = __builtin_elementwise_max(acc, zf4);
  }
#pragma unroll
  for (int r = 0; r < 4; ++r) {
    H4 pk;
    pk.p[0] = pkrtz(D1[0][r], D1[1][r]);
    pk.p[1] = pkrtz(D1[2][r], D1[3][r]);
    *(h16x4*)&h2T[4*q + r][4*c] = pk.v;
  }
  h16x8 R2[4][2];
#pragma unroll
  for (int ct = 0; ct < 4; ++ct)
#pragma unroll
    for (int ks = 0; ks < 2; ++ks)
      R2[ct][ks] = *(const h16x8*)&Q2T[16*ct + c][32*ks + 8*q];
  float rb2v[4];
#pragma unroll
  for (int ct = 0; ct < 4; ++ct) rb2v[ct] = rb2[16*ct + c];

  __builtin_amdgcn_s_waitcnt(0xC07F);
  __builtin_amdgcn_wave_barrier();
  h16x8 A2r[2];
#pragma unroll
  for (int ks = 0; ks < 2; ++ks)
    A2r[ks] = *(const h16x8*)&h2T[c][32*ks + 8*q];
  __builtin_amdgcn_wave_barrier();

  // rho layer 2
  fx4 D2[4];
#pragma unroll
  for (int ct = 0; ct < 4; ++ct) {
    fx4 acc = {rb2v[ct], rb2v[ct], rb2v[ct], rb2v[ct]};
    acc = mfma16(A2r[0], R2[ct][0], acc);
    acc = mfma16(A2r[1], R2[ct][1], acc);
    D2[ct] = __builtin_elementwise_max(acc, zf4);
  }
#pragma unroll
  for (int r = 0; r < 4; ++r) {
    H4 pk;
    pk.p[0] = pkrtz(D2[0][r], D2[1][r]);
    pk.p[1] = pkrtz(D2[2][r], D2[3][r]);
    *(h16x4*)&h2T[4*q + r][4*c] = pk.v;
  }
  h16x8 R3[2][2];
#pragma unroll
  for (int ct = 0; ct < 2; ++ct)
#pragma unroll
    for (int ks = 0; ks < 2; ++ks)
      R3[ct][ks] = *(const h16x8*)&Q3T[16*ct + c][32*ks + 8*q];
  float rb3v[2];
#pragma unroll
  for (int ct = 0; ct < 2; ++ct) rb3v[ct] = rb3[16*ct + c];

  __builtin_amdgcn_s_waitcnt(0xC07F);
  __builtin_amdgcn_wave_barrier();
  h16x8 A3r[2];
#pragma unroll
  for (int ks = 0; ks < 2; ++ks)
    A3r[ks] = *(const h16x8*)&h2T[c][32*ks + 8*q];
  __builtin_amdgcn_wave_barrier();

  // rho layer 3 + store
  fx4 D3[2];
#pragma unroll
  for (int ct = 0; ct < 2; ++ct) {
    fx4 acc = {rb3v[ct], rb3v[ct], rb3v[ct], rb3v[ct]};
    acc = mfma16(A3r[0], R3[ct][0], acc);
    acc = mfma16(A3r[1], R3[ct][1], acc);
    D3[ct] = acc;
  }
  const int srow = sWave + 4*q;
#pragma unroll
  for (int ct = 0; ct < 2; ++ct)
#pragma unroll
    for (int r = 0; r < 4; ++r)
      out[(size_t)(srow + r)*32 + 16*ct + c] = D3[ct][r];
}

extern "C" void kernel_launch(void* const* d_in, const int* in_sizes, int n_in,
                              void* d_out, int out_size, void* d_ws, size_t ws_size,
                              hipStream_t stream) {
  const float* x   = (const float*)d_in[0];
  const float* vel = (const float*)d_in[1];
  const float* pW1 = (const float*)d_in[2];
  const float* pb1 = (const float*)d_in[3];
  const float* pW2 = (const float*)d_in[4];
  const float* pb2 = (const float*)d_in[5];
  const float* pW3 = (const float*)d_in[6];
  const float* pb3 = (const float*)d_in[7];
  const float* rW1 = (const float*)d_in[8];
  const float* rb1 = (const float*)d_in[9];
  const float* rW2 = (const float*)d_in[10];
  const float* rb2 = (const float*)d_in[11];
  const float* rW3 = (const float*)d_in[12];
  const float* rb3 = (const float*)d_in[13];
  float* out = (float*)d_out;

  const int B = in_sizes[0] / 64;        // x is [B, 64]
  deepset_main<<<dim3(B / 128), dim3(512), 0, stream>>>(
      x, vel, pW1, pb1, pW2, pb2, pW3, pb3,
      rW1, rb1, rW2, rb2, rW3, rb3, out);
}

// Round 9
// 112.188 us; speedup vs baseline: 2.5737x; 1.0142x over previous
//
#include <hip/hip_runtime.h>

typedef _Float16 h16x8 __attribute__((ext_vector_type(8)));
typedef _Float16 h16x4 __attribute__((ext_vector_type(4)));
typedef _Float16 h16x2 __attribute__((ext_vector_type(2)));
typedef float    fx4   __attribute__((ext_vector_type(4)));

static __device__ __forceinline__ fx4 mfma16(h16x8 a, h16x8 b, fx4 c) {
  return __builtin_amdgcn_mfma_f32_16x16x32_f16(a, b, c, 0, 0, 0);
}
static __device__ __forceinline__ h16x2 pkrtz(float a, float b) {
  auto r = __builtin_amdgcn_cvt_pkrtz(a, b);        // v_cvt_pkrtz_f16_f32
  h16x2 o; __builtin_memcpy(&o, &r, sizeof(o)); return o;
}
union ABfrag { h16x2 p[4]; h16x8 v; };
union H4     { h16x2 p[2]; h16x4 v; };

// R9: the phi loop was MFMA-dest->VALU-read hazard-bound (R8 arithmetic: VALU
// issue ~4.5us/SIMD, MFMA pipe ~8.3us/CU, kernel 35us -> ~60% no-issue stall;
// only 4 waves/SIMD resident — VGPR~100 hard-caps 16 waves/CU per the
// vgpr={64,128,256} halving thresholds — so TLP can't hide the ~20cyc/read
// hazard on the 8 pool reads right after each MFMA batch).
// Fix: depth-1 software pipeline. Issue obstacle o+1's 8 MFMAs BEFORE pooling
// obstacle o's acc — every pool read is separated from its producer by a full
// MFMA batch (~155 cyc matrix-pipe time). +16 VGPR (acc dbuf), live ~110<128.
// One garbage batch at the wrap (never pooled) keeps the loop branch-free.
// Retained: block-shared LDS weight tiles (R7), f16 packed pool (R8), weights
// from d_in (d_ws uncached, R4), (512,4) VGPR cap 128 (R5/R6).
//
// Transpose permutation: writer (lane c, col-tile ct) stores feature f=16*ct+c
// at position p=4*c+ct (one ds_write_b64); consumer weight rows are staged at
// f = 16*(p&3)+(p>>2) so K-order matches (dot products are order-invariant).

__global__ __launch_bounds__(512, 4)
void deepset_main(const float* __restrict__ x,   const float* __restrict__ vel,
                  const float* __restrict__ pW1, const float* __restrict__ pb1,
                  const float* __restrict__ pW2, const float* __restrict__ pb2,
                  const float* __restrict__ pW3, const float* __restrict__ pb3,
                  const float* __restrict__ rW1, const float* __restrict__ rb1,
                  const float* __restrict__ rW2, const float* __restrict__ rb2,
                  const float* __restrict__ rW3, const float* __restrict__ rb3,
                  float* __restrict__ out)
{
  __shared__ __align__(16) _Float16 L2T[64][72];   // phi W2, natural rows
  __shared__ __align__(16) _Float16 L3T[64][72];   // phi W3, permuted rows
  __shared__ __align__(16) _Float16 Q1T[64][72];   // rho W1, permuted rows
  __shared__ __align__(16) _Float16 Q2T[64][72];   // rho W2, permuted rows
  __shared__ __align__(16) _Float16 Q3T[32][72];   // rho W3, permuted rows
  __shared__ __align__(16) _Float16 xh[8][16][72]; // per-wave x tile / transpose buf

  const int tid  = threadIdx.x;
  const int wave = tid >> 6;
  const int lane = tid & 63;
  const int q    = lane >> 4;
  const int c    = lane & 15;
  const int sBase = blockIdx.x * 128;
  const int sWave = sBase + wave * 16;

  // ---- cooperative weight staging: coalesced row loads, b128 LDS writes.
  {
    const int col = tid & 63;
    const int kg  = tid >> 6;
    float v2[8], v3[8], r1[8], r2[8];
#pragma unroll
    for (int j = 0; j < 8; ++j) {
      const int p = 8*kg + j;
      const int f = 16*(p & 3) + (p >> 2);         // permuted source row
      v2[j] = pW2[p*64 + col];
      v3[j] = pW3[f*64 + col];
      r1[j] = rW1[f*64 + col];
      r2[j] = rW2[f*64 + col];
    }
    h16x8 h2v, h3v, h1v, h2r;
#pragma unroll
    for (int j = 0; j < 8; ++j) { h2v[j] = (_Float16)v2[j]; h3v[j] = (_Float16)v3[j];
                                  h1v[j] = (_Float16)r1[j]; h2r[j] = (_Float16)r2[j]; }
    *(h16x8*)&L2T[col][8*kg] = h2v;
    *(h16x8*)&L3T[col][8*kg] = h3v;
    *(h16x8*)&Q1T[col][8*kg] = h1v;
    *(h16x8*)&Q2T[col][8*kg] = h2r;
    if (tid < 256) {                               // rho W3 is 64x32
      const int col3 = tid & 31;
      const int kg3  = tid >> 5;
      float r3[8];
#pragma unroll
      for (int j = 0; j < 8; ++j) {
        const int p = 8*kg3 + j;
        const int f = 16*(p & 3) + (p >> 2);
        r3[j] = rW3[f*32 + col3];
      }
      h16x8 h3r;
#pragma unroll
      for (int j = 0; j < 8; ++j) h3r[j] = (_Float16)r3[j];
      *(h16x8*)&Q3T[col3][8*kg3] = h3r;
    }
  }

  // ---- x tile -> per-wave LDS (f16)
  {
    const int s0 = lane >> 2, ch = (lane & 3) * 16;
#pragma unroll
    for (int k = 0; k < 4; ++k) {
      const fx4 g = *(const fx4*)(x + (size_t)(sWave + s0)*64 + ch + 4*k);
      H4 pk; pk.p[0] = pkrtz(g[0], g[1]); pk.p[1] = pkrtz(g[2], g[3]);
      *(h16x4*)&xh[wave][s0][ch + 4*k] = pk.v;
    }
  }
  const float2 vc = *(const float2*)(vel + 2*(size_t)(sWave + c)); // lane's state

  // ---- layer-1 constants (same for all waves -> L2-hot)
  h16x2 wx[2][4], wy[2][4], vbp[2][4];
#pragma unroll
  for (int ks = 0; ks < 2; ++ks)
#pragma unroll
    for (int t = 0; t < 4; ++t) {
      const int f0 = 32*ks + 8*q + 2*t;
      wx[ks][t] = pkrtz(pW1[f0], pW1[f0 + 1]);
      wy[ks][t] = pkrtz(pW1[64 + f0], pW1[64 + f0 + 1]);
      const float v0 = fmaf(vc.x, pW1[128 + f0],     fmaf(vc.y, pW1[192 + f0],     pb1[f0]));
      const float v1 = fmaf(vc.x, pW1[128 + f0 + 1], fmaf(vc.y, pW1[192 + f0 + 1], pb1[f0 + 1]));
      vbp[ks][t] = pkrtz(v0, v1);
    }
  float b2v[4];
#pragma unroll
  for (int ct = 0; ct < 4; ++ct) b2v[ct] = pb2[16*ct + c];

  __syncthreads();                         // weight tiles + x tiles ready

  // ---- phi W2 B-fragments: one ds_read_b128 each
  h16x8 B2[4][2];
#pragma unroll
  for (int ct = 0; ct < 4; ++ct)
#pragma unroll
    for (int ks = 0; ks < 2; ++ks)
      B2[ct][ks] = *(const h16x8*)&L2T[16*ct + c][32*ks + 8*q];

  const h16x2 z2 = {(_Float16)0.f, (_Float16)0.f};
  h16x2 Xh[4][2] = {{z2, z2}, {z2, z2}, {z2, z2}, {z2, z2}};  // f16 pooled X

  // layer-1 generator: A-fragment for one obstacle (packed f16 VALU)
#define L1GEN(DST, OXH, OYH)                                                 \
  {                                                                          \
    h16x2 ox, oy;                                                            \
    ox[0] = (OXH); ox[1] = (OXH); oy[0] = (OYH); oy[1] = (OYH);              \
    _Pragma("unroll")                                                        \
    for (int ks = 0; ks < 2; ++ks) {                                         \
      ABfrag a;                                                              \
      _Pragma("unroll")                                                      \
      for (int t = 0; t < 4; ++t) {                                          \
        const h16x2 h = ox * wx[ks][t] + oy * wy[ks][t] + vbp[ks][t];        \
        a.p[t] = __builtin_elementwise_max(h, z2);                           \
      }                                                                      \
      DST[ks] = a.v;                                                         \
    }                                                                        \
  }

#define ISSUE(ACC, A1)                                                       \
  _Pragma("unroll")                                                          \
  for (int ct = 0; ct < 4; ++ct) {                                           \
    fx4 t_ = {b2v[ct], b2v[ct], b2v[ct], b2v[ct]};                           \
    t_ = mfma16(A1[0], B2[ct][0], t_);                                       \
    ACC[ct] = mfma16(A1[1], B2[ct][1], t_);                                  \
  }

#define POOL(ACC)                                                            \
  _Pragma("unroll")                                                          \
  for (int ct = 0; ct < 4; ++ct) {                                           \
    const h16x2 lo = pkrtz(ACC[ct][0], ACC[ct][1]);                          \
    const h16x2 hi = pkrtz(ACC[ct][2], ACC[ct][3]);                          \
    Xh[ct][0] += __builtin_elementwise_max(lo, z2);                          \
    Xh[ct][1] += __builtin_elementwise_max(hi, z2);                          \
  }

  // ================= phi + pool: depth-1 software pipeline ==================
  h16x8 A1a[2], A1b[2];
  fx4 accA[4], accB[4];
  h16x4 p_cur = *(const h16x4*)&xh[wave][c][0];

  L1GEN(A1a, p_cur[0], p_cur[1])           // obstacle 0
  ISSUE(accA, A1a)

#pragma unroll 1
  for (int oo = 0; oo < 16; ++oo) {
    const h16x4 p_nxt = *(const h16x4*)&xh[wave][c][4*((oo + 1) & 15)];
    L1GEN(A1b, p_cur[2], p_cur[3])         // obstacle 2oo+1
    ISSUE(accB, A1b)
    POOL(accA)                             // obstacle 2oo (one full batch behind)
    L1GEN(A1a, p_nxt[0], p_nxt[1])         // obstacle 2oo+2 (garbage at oo=15,
    ISSUE(accA, A1a)                       //  wraps to ob 0 — never pooled)
    POOL(accB)                             // obstacle 2oo+1
    p_cur = p_nxt;
  }
#undef L1GEN
#undef ISSUE
#undef POOL

  // ---- tail: reuse this wave's xh tile as the transpose buffer
  _Float16 (*h2T)[72] = xh[wave];

  // X (f16 pairs) -> permuted transpose write
#pragma unroll
  for (int r = 0; r < 4; ++r) {
    h16x4 pk;
#pragma unroll
    for (int ct = 0; ct < 4; ++ct) pk[ct] = Xh[ct][r >> 1][r & 1];
    *(h16x4*)&h2T[4*q + r][4*c] = pk;
  }
  // phi W3 fragments (permuted rows already staged)
  h16x8 B3[4][2];
#pragma unroll
  for (int ct = 0; ct < 4; ++ct)
#pragma unroll
    for (int ks = 0; ks < 2; ++ks)
      B3[ct][ks] = *(const h16x8*)&L3T[16*ct + c][32*ks + 8*q];
  float b3s[4];
#pragma unroll
  for (int ct = 0; ct < 4; ++ct) b3s[ct] = 32.f * pb3[16*ct + c];

  __builtin_amdgcn_s_waitcnt(0xC07F);      // lgkmcnt(0)
  __builtin_amdgcn_wave_barrier();
  h16x8 AX[2];
#pragma unroll
  for (int ks = 0; ks < 2; ++ks)
    AX[ks] = *(const h16x8*)&h2T[c][32*ks + 8*q];
  __builtin_amdgcn_wave_barrier();

  // phi layer 3 (linear, pooled): X = W3^T(sum relu) + 32*b3
  fx4 C3[4];
#pragma unroll
  for (int ct = 0; ct < 4; ++ct) {
    fx4 acc = {b3s[ct], b3s[ct], b3s[ct], b3s[ct]};
    acc = mfma16(AX[0], B3[ct][0], acc);
    acc = mfma16(AX[1], B3[ct][1], acc);
    C3[ct] = acc;
  }
#pragma unroll
  for (int r = 0; r < 4; ++r) {
    H4 pk;
    pk.p[0] = pkrtz(C3[0][r], C3[1][r]);
    pk.p[1] = pkrtz(C3[2][r], C3[3][r]);
    *(h16x4*)&h2T[4*q + r][4*c] = pk.v;
  }
  h16x8 R1[4][2];
#pragma unroll
  for (int ct = 0; ct < 4; ++ct)
#pragma unroll
    for (int ks = 0; ks < 2; ++ks)
      R1[ct][ks] = *(const h16x8*)&Q1T[16*ct + c][32*ks + 8*q];
  float rb1v[4];
#pragma unroll
  for (int ct = 0; ct < 4; ++ct) rb1v[ct] = rb1[16*ct + c];

  __builtin_amdgcn_s_waitcnt(0xC07F);
  __builtin_amdgcn_wave_barrier();
  h16x8 A1r[2];
#pragma unroll
  for (int ks = 0; ks < 2; ++ks)
    A1r[ks] = *(const h16x8*)&h2T[c][32*ks + 8*q];
  __builtin_amdgcn_wave_barrier();

  // rho layer 1
  const fx4 zf4 = {0.f, 0.f, 0.f, 0.f};
  fx4 D1[4];
#pragma unroll
  for (int ct = 0; ct < 4; ++ct) {
    fx4 acc = {rb1v[ct], rb1v[ct], rb1v[ct], rb1v[ct]};
    acc = mfma16(A1r[0], R1[ct][0], acc);
    acc = mfma16(A1r[1], R1[ct][1], acc);
    D1[ct] = __builtin_elementwise_max(acc, zf4);
  }
#pragma unroll
  for (int r = 0; r < 4; ++r) {
    H4 pk;
    pk.p[0] = pkrtz(D1[0][r], D1[1][r]);
    pk.p[1] = pkrtz(D1[2][r], D1[3][r]);
    *(h16x4*)&h2T[4*q + r][4*c] = pk.v;
  }
  h16x8 R2[4][2];
#pragma unroll
  for (int ct = 0; ct < 4; ++ct)
#pragma unroll
    for (int ks = 0; ks < 2; ++ks)
      R2[ct][ks] = *(const h16x8*)&Q2T[16*ct + c][32*ks + 8*q];
  float rb2v[4];
#pragma unroll
  for (int ct = 0; ct < 4; ++ct) rb2v[ct] = rb2[16*ct + c];

  __builtin_amdgcn_s_waitcnt(0xC07F);
  __builtin_amdgcn_wave_barrier();
  h16x8 A2r[2];
#pragma unroll
  for (int ks = 0; ks < 2; ++ks)
    A2r[ks] = *(const h16x8*)&h2T[c][32*ks + 8*q];
  __builtin_amdgcn_wave_barrier();

  // rho layer 2
  fx4 D2[4];
#pragma unroll
  for (int ct = 0; ct < 4; ++ct) {
    fx4 acc = {rb2v[ct], rb2v[ct], rb2v[ct], rb2v[ct]};
    acc = mfma16(A2r[0], R2[ct][0], acc);
    acc = mfma16(A2r[1], R2[ct][1], acc);
    D2[ct] = __builtin_elementwise_max(acc, zf4);
  }
#pragma unroll
  for (int r = 0; r < 4; ++r) {
    H4 pk;
    pk.p[0] = pkrtz(D2[0][r], D2[1][r]);
    pk.p[1] = pkrtz(D2[2][r], D2[3][r]);
    *(h16x4*)&h2T[4*q + r][4*c] = pk.v;
  }
  h16x8 R3[2][2];
#pragma unroll
  for (int ct = 0; ct < 2; ++ct)
#pragma unroll
    for (int ks = 0; ks < 2; ++ks)
      R3[ct][ks] = *(const h16x8*)&Q3T[16*ct + c][32*ks + 8*q];
  float rb3v[2];
#pragma unroll
  for (int ct = 0; ct < 2; ++ct) rb3v[ct] = rb3[16*ct + c];

  __builtin_amdgcn_s_waitcnt(0xC07F);
  __builtin_amdgcn_wave_barrier();
  h16x8 A3r[2];
#pragma unroll
  for (int ks = 0; ks < 2; ++ks)
    A3r[ks] = *(const h16x8*)&h2T[c][32*ks + 8*q];
  __builtin_amdgcn_wave_barrier();

  // rho layer 3 + store
  fx4 D3[2];
#pragma unroll
  for (int ct = 0; ct < 2; ++ct) {
    fx4 acc = {rb3v[ct], rb3v[ct], rb3v[ct], rb3v[ct]};
    acc = mfma16(A3r[0], R3[ct][0], acc);
    acc = mfma16(A3r[1], R3[ct][1], acc);
    D3[ct] = acc;
  }
  const int srow = sWave + 4*q;
#pragma unroll
  for (int ct = 0; ct < 2; ++ct)
#pragma unroll
    for (int r = 0; r < 4; ++r)
      out[(size_t)(srow + r)*32 + 16*ct + c] = D3[ct][r];
}

extern "C" void kernel_launch(void* const* d_in, const int* in_sizes, int n_in,
                              void* d_out, int out_size, void* d_ws, size_t ws_size,
                              hipStream_t stream) {
  const float* x   = (const float*)d_in[0];
  const float* vel = (const float*)d_in[1];
  const float* pW1 = (const float*)d_in[2];
  const float* pb1 = (const float*)d_in[3];
  const float* pW2 = (const float*)d_in[4];
  const float* pb2 = (const float*)d_in[5];
  const float* pW3 = (const float*)d_in[6];
  const float* pb3 = (const float*)d_in[7];
  const float* rW1 = (const float*)d_in[8];
  const float* rb1 = (const float*)d_in[9];
  const float* rW2 = (const float*)d_in[10];
  const float* rb2 = (const float*)d_in[11];
  const float* rW3 = (const float*)d_in[12];
  const float* rb3 = (const float*)d_in[13];
  float* out = (float*)d_out;

  const int B = in_sizes[0] / 64;        // x is [B, 64]
  deepset_main<<<dim3(B / 128), dim3(512), 0, stream>>>(
      x, vel, pW1, pb1, pW2, pb2, pW3, pb3,
      rW1, rb1, rW2, rb2, rW3, rb3, out);
}